// Round 4
// baseline (66.353 us; speedup 1.0000x reference)
//
#include <hip/hip_runtime.h>

typedef float v4f __attribute__((ext_vector_type(4)));

#define NATOM 128
#define FEAT 128
#define FILT 128
#define BATCH 8

// Kernel 1: s1[row,k] = sum_f sf[row,f]*W[f,k] + bias[k]; s2 likewise with W2.
// 256 blocks x 256 threads; each block does 4 rows, so W (128 KB) is read
// 256x total (32 MB L2) instead of 1024x. sf staged transposed in LDS so the
// 4-row accumulator is a single v4f FMA per f.
__global__ __launch_bounds__(256) void s_gemm_kernel(
    const float* __restrict__ sf, const float* __restrict__ W,
    const float* __restrict__ bias, float* __restrict__ s1,
    float* __restrict__ s2) {
  const int r0 = blockIdx.x * 4;  // first of 4 rows (row = b*N+n)
  const int tid = threadIdx.x;
  const int k = tid & (FILT - 1);
  const int which = tid >> 7;  // 0 -> s1, 1 -> s2

  __shared__ float sfT[FEAT * 4];  // [f][r]
  {
    const int row = tid >> 7, f0 = tid & 127;
    sfT[f0 * 4 + row] = sf[(r0 + row) * FEAT + f0];
    sfT[f0 * 4 + row + 2] = sf[(r0 + row + 2) * FEAT + f0];
  }
  __syncthreads();

  const float* Wcol = W + which * FEAT * FILT + k;
  v4f acc = {0.f, 0.f, 0.f, 0.f};
#pragma unroll
  for (int f = 0; f < FEAT; ++f) {
    const float w = Wcol[f * FILT];
    acc += *reinterpret_cast<const v4f*>(&sfT[f * 4]) * w;
  }

  float* dst = (which ? s2 : s1) + r0 * FILT + k;
  const float bb = which ? 0.f : bias[k];
#pragma unroll
  for (int r = 0; r < 4; ++r) dst[r * FILT] = acc[r] + bb;
}

// Kernel 2: out[b,i,j,c,k] = (s1[b,i,k] + s2[b,j,k]) * dist[b,i,j,c]
// 1024 blocks = 8b x 32 i-groups x 4 j-quarters. Each block: 4 i-rows x 32 j.
// i-tiling x4 reuses each s2 row from registers -> s2 L2-read traffic 64->16MB
// (stop reads from contending with the 201MB write stream in L2).
// dist slice (4x32x3) in LDS; plain (cached) float4 stores.
__global__ __launch_bounds__(256) void expand_kernel(
    const float* __restrict__ s1, const float* __restrict__ s2,
    const float* __restrict__ dist, float* __restrict__ out) {
  const int blk = blockIdx.x;
  const int jq = blk & 3;          // j quarter
  const int ig = (blk >> 2) & 31;  // i group
  const int b = blk >> 7;
  const int tid = threadIdx.x;
  const int kq = (tid & 31) << 2;  // k: 0..124 step 4
  const int jl = tid >> 5;         // 0..7
  const int i0 = ig * 4, j0 = jq * 32;

  // Stage dist[b, i0..i0+4, j0..j0+32, 0..3] -> dl[ii][jj][c] (384 floats)
  __shared__ float dl[4 * 32 * 3];
  {
    const size_t dbase = ((size_t)(b * NATOM + i0) * NATOM + j0) * 3;
    for (int idx = tid; idx < 384; idx += 256) {
      const int ii = idx / 96, rem = idx - ii * 96;  // rem = jj*3+c
      dl[idx] = dist[dbase + (size_t)ii * NATOM * 3 + rem];
    }
  }

  v4f s1v[4];
#pragma unroll
  for (int ii = 0; ii < 4; ++ii)
    s1v[ii] = *reinterpret_cast<const v4f*>(s1 + (b * NATOM + i0 + ii) * FILT + kq);

  const float* s2base = s2 + (size_t)(b * NATOM + j0) * FILT;
  float* obase0 = out + (((size_t)(b * NATOM + i0) * NATOM + j0) * 3) * FILT;

  __syncthreads();

#pragma unroll
  for (int jj0 = 0; jj0 < 32; jj0 += 8) {
    const int jj = jj0 + jl;
    const v4f s2v = *reinterpret_cast<const v4f*>(s2base + jj * FILT + kq);
#pragma unroll
    for (int ii = 0; ii < 4; ++ii) {
      const v4f p = s1v[ii] + s2v;
      const float d0 = dl[(ii * 32 + jj) * 3 + 0];
      const float d1 = dl[(ii * 32 + jj) * 3 + 1];
      const float d2 = dl[(ii * 32 + jj) * 3 + 2];
      float* o = obase0 + (size_t)ii * NATOM * 3 * FILT + (size_t)jj * 3 * FILT + kq;
      *reinterpret_cast<v4f*>(o) = p * d0;
      *reinterpret_cast<v4f*>(o + FILT) = p * d1;
      *reinterpret_cast<v4f*>(o + 2 * FILT) = p * d2;
    }
  }
}

extern "C" void kernel_launch(void* const* d_in, const int* in_sizes, int n_in,
                              void* d_out, int out_size, void* d_ws, size_t ws_size,
                              hipStream_t stream) {
  const float* sf   = (const float*)d_in[0];  // (8,128,128)
  const float* dist = (const float*)d_in[1];  // (8,128,128,3)
  const float* W    = (const float*)d_in[2];  // (256,128)
  const float* bias = (const float*)d_in[3];  // (1,128)
  float* out = (float*)d_out;                 // (8,128,128,3,128)

  float* s1 = (float*)d_ws;  // 1024*128 f32
  float* s2 = s1 + BATCH * NATOM * FILT;

  s_gemm_kernel<<<BATCH * NATOM / 4, 256, 0, stream>>>(sf, W, bias, s1, s2);
  expand_kernel<<<BATCH * 32 * 4, 256, 0, stream>>>(s1, s2, dist, out);
}

// Round 5
// 42.840 us; speedup vs baseline: 1.5488x; 1.5488x over previous
//
#include <hip/hip_runtime.h>

typedef float v4f __attribute__((ext_vector_type(4)));

#define NATOM 128
#define FEAT 128
#define FILT 128
#define BATCH 8

// Kernel 1 (reverted to R3 form — R4's 4-row variant was latency-bound:
// VGPR 256, occupancy 0.065%, 127us): one block per row, 256 threads,
// tid = which*128 + k; scalar 128-FMA dot per thread, W reads coalesced.
__global__ __launch_bounds__(256) void s_gemm_kernel(
    const float* __restrict__ sf, const float* __restrict__ W,
    const float* __restrict__ bias, float* __restrict__ s1,
    float* __restrict__ s2) {
  const int row = blockIdx.x;
  const int tid = threadIdx.x;
  const int k = tid & (FILT - 1);
  const int which = tid >> 7;  // 0 -> s1, 1 -> s2

  __shared__ float sfrow[FEAT];
  if (tid < FEAT) sfrow[tid] = sf[row * FEAT + tid];
  __syncthreads();

  const float* Wcol = W + which * FEAT * FILT + k;
  float acc = 0.f;
#pragma unroll
  for (int f = 0; f < FEAT; ++f) acc = fmaf(sfrow[f], Wcol[f * FILT], acc);

  if (which == 0)
    s1[row * FILT + k] = acc + bias[k];
  else
    s2[row * FILT + k] = acc;
}

// Kernel 2 (kept from R4): out[b,i,j,c,k] = (s1[b,i,k]+s2[b,j,k])*dist[b,i,j,c]
// 1024 blocks = 8b x 32 i-groups x 4 j-quarters. Each block: 4 i-rows x 32 j.
// i-tiling x4 reuses each s2 row from registers -> s2 L2-read traffic 64->16MB.
// dist slice (4x32x3) in LDS; plain (cached) float4 stores.
__global__ __launch_bounds__(256) void expand_kernel(
    const float* __restrict__ s1, const float* __restrict__ s2,
    const float* __restrict__ dist, float* __restrict__ out) {
  const int blk = blockIdx.x;
  const int jq = blk & 3;          // j quarter
  const int ig = (blk >> 2) & 31;  // i group
  const int b = blk >> 7;
  const int tid = threadIdx.x;
  const int kq = (tid & 31) << 2;  // k: 0..124 step 4
  const int jl = tid >> 5;         // 0..7
  const int i0 = ig * 4, j0 = jq * 32;

  // Stage dist[b, i0..i0+4, j0..j0+32, 0..3] -> dl[ii][jj][c] (384 floats)
  __shared__ float dl[4 * 32 * 3];
  {
    const size_t dbase = ((size_t)(b * NATOM + i0) * NATOM + j0) * 3;
    for (int idx = tid; idx < 384; idx += 256) {
      const int ii = idx / 96, rem = idx - ii * 96;  // rem = jj*3+c
      dl[idx] = dist[dbase + (size_t)ii * NATOM * 3 + rem];
    }
  }

  v4f s1v[4];
#pragma unroll
  for (int ii = 0; ii < 4; ++ii)
    s1v[ii] = *reinterpret_cast<const v4f*>(s1 + (b * NATOM + i0 + ii) * FILT + kq);

  const float* s2base = s2 + (size_t)(b * NATOM + j0) * FILT;
  float* obase0 = out + (((size_t)(b * NATOM + i0) * NATOM + j0) * 3) * FILT;

  __syncthreads();

#pragma unroll
  for (int jj0 = 0; jj0 < 32; jj0 += 8) {
    const int jj = jj0 + jl;
    const v4f s2v = *reinterpret_cast<const v4f*>(s2base + jj * FILT + kq);
#pragma unroll
    for (int ii = 0; ii < 4; ++ii) {
      const v4f p = s1v[ii] + s2v;
      const float d0 = dl[(ii * 32 + jj) * 3 + 0];
      const float d1 = dl[(ii * 32 + jj) * 3 + 1];
      const float d2 = dl[(ii * 32 + jj) * 3 + 2];
      float* o = obase0 + (size_t)ii * NATOM * 3 * FILT + (size_t)jj * 3 * FILT + kq;
      *reinterpret_cast<v4f*>(o) = p * d0;
      *reinterpret_cast<v4f*>(o + FILT) = p * d1;
      *reinterpret_cast<v4f*>(o + 2 * FILT) = p * d2;
    }
  }
}

extern "C" void kernel_launch(void* const* d_in, const int* in_sizes, int n_in,
                              void* d_out, int out_size, void* d_ws, size_t ws_size,
                              hipStream_t stream) {
  const float* sf   = (const float*)d_in[0];  // (8,128,128)
  const float* dist = (const float*)d_in[1];  // (8,128,128,3)
  const float* W    = (const float*)d_in[2];  // (256,128)
  const float* bias = (const float*)d_in[3];  // (1,128)
  float* out = (float*)d_out;                 // (8,128,128,3,128)

  float* s1 = (float*)d_ws;  // 1024*128 f32
  float* s2 = s1 + BATCH * NATOM * FILT;

  s_gemm_kernel<<<BATCH * NATOM, 256, 0, stream>>>(sf, W, bias, s1, s2);
  expand_kernel<<<BATCH * 32 * 4, 256, 0, stream>>>(s1, s2, dist, out);
}